// Round 1
// baseline (2738.418 us; speedup 1.0000x reference)
//
#include <hip/hip_runtime.h>
#include <math.h>

#define NPTS    131072
#define PPB     16          // points per block
#define ROWS    64          // 4 rows per point: value + 3 tangents
#define THREADS 128
#define KC      32          // k-chunk staged into LDS
#define WSTR    132         // padded W_T row stride (floats, 16B-aligned)
#define DIMX    40          // posenc dim 39, zero-padded to 40

__device__ __forceinline__ void cross3(const float a[3], const float b[3], float o[3]) {
  o[0] = a[1]*b[2] - a[2]*b[1];
  o[1] = a[2]*b[0] - a[0]*b[2];
  o[2] = a[0]*b[1] - a[1]*b[0];
}
__device__ __forceinline__ float dot3(const float a[3], const float b[3]) {
  return a[0]*b[0] + a[1]*b[1] + a[2]*b[2];
}

__global__ __launch_bounds__(THREADS)
void nerfies_fused(const float* __restrict__ x,
                   const float* __restrict__ W_in,   // [128][39]
                   const float* __restrict__ b_in,   // [128]
                   const float* __restrict__ Ws,     // [6][128][128]
                   const float* __restrict__ bs,     // [6][128]
                   const float* __restrict__ Ww,     // [3][128]
                   const float* __restrict__ bw,     // [3]
                   const float* __restrict__ Wv,     // [3][128]
                   const float* __restrict__ bv,     // [3]
                   const int*   __restrict__ iterp,
                   float* __restrict__ out)
{
  __shared__ __align__(16) float sA[128 * ROWS];   // A_T[k][r]  32 KB
  __shared__ __align__(16) float sW[KC * WSTR];    // W_T[kk][c] 16.9 KB
  __shared__ __align__(16) float sX[PPB * 3];
  __shared__ __align__(16) float sH[ROWS * 8];     // head outs [r][o], o<6 used

  const int tid = threadIdx.x;
  const int p0  = blockIdx.x * PPB;
  const int tr  = tid >> 4;   // 0..7 : rows 8*tr..+7 (covers points 2tr,2tr+1 incl. their value rows)
  const int tc  = tid & 15;   // 0..15: cols 8*tc..+7

  if (tid < PPB * 3) sX[tid] = x[p0 * 3 + tid];

  // robust iter decode (int32 / int64-LE / float32 all give 2500)
  int iraw = iterp[0];
  float it = (iraw > 0 && iraw < 100000000) ? (float)iraw : ((const float*)iterp)[0];

  const float aM = 6.0f * it / 3000.0f;   // M*it/(0.6*5000)
  float wa[6], mulf[6];
  #pragma unroll
  for (int j = 0; j < 6; ++j) {
    float t = fminf(fmaxf(aM - (float)j, 0.0f), 1.0f);
    wa[j]   = (1.0f - cosf(t * 3.14f)) * 0.5f;
    mulf[j] = exp2f((float)(j - 3)) * 3.14f;   // 2^(j+K0) * 3.14
  }
  __syncthreads();  // sX visible

  // ---- positional encoding + tangent seeds into A_T[k][r] (k<40, r = 4p+d) ----
  for (int idx = tid; idx < DIMX * ROWS; idx += THREADS) {
    int k = idx >> 6;
    int r = idx & 63;
    int p = r >> 2, d = r & 3;       // d==0 value row, d-1 = tangent dir
    float val = 0.0f;
    if (k < 3) {
      val = (d == 0) ? sX[p*3 + k] : ((k == d - 1) ? 1.0f : 0.0f);
    } else if (k < 39) {
      int kk = k - 3;
      int i  = kk / 12;              // axis
      int rm = kk - i * 12;
      int t  = rm / 6;               // 0=sin 1=cos
      int j  = rm - t * 6;           // freq
      float ang = sX[p*3 + i] * mulf[j];
      float sv = sinf(ang), cv = cosf(ang);
      if (d == 0)           val = (t == 0 ? sv : cv) * wa[j];
      else if (i == d - 1)  val = (t == 0 ? cv : -sv) * (mulf[j] * wa[j]);
    }
    sA[k * ROWS + r] = val;   // k==39 pad stays 0
  }

  float acc[8][8];

  // ---- 7 GEMM layers: layer0 = input (leaky 0.01), layers 1..6 hidden (relu) ----
  for (int layer = 0; layer <= 6; ++layer) {
    const float* Wg; const float* bg; int Kin, Kpad; float slope;
    if (layer == 0) { Wg = W_in; bg = b_in; Kin = 39;  Kpad = DIMX; slope = 0.01f; }
    else            { Wg = Ws + (layer-1)*16384; bg = bs + (layer-1)*128; Kin = 128; Kpad = 128; slope = 0.0f; }

    // bias only on value rows (i = 0 and 4)
    {
      float4 b0 = *(const float4*)&bg[8*tc];
      float4 b1 = *(const float4*)&bg[8*tc + 4];
      #pragma unroll
      for (int i = 0; i < 8; ++i)
        #pragma unroll
        for (int j = 0; j < 8; ++j) acc[i][j] = 0.0f;
      acc[0][0]=b0.x; acc[0][1]=b0.y; acc[0][2]=b0.z; acc[0][3]=b0.w;
      acc[0][4]=b1.x; acc[0][5]=b1.y; acc[0][6]=b1.z; acc[0][7]=b1.w;
      #pragma unroll
      for (int j = 0; j < 8; ++j) acc[4][j] = acc[0][j];
    }

    for (int kc = 0; kc < Kpad; kc += KC) {
      int kcn = (Kpad - kc < KC) ? (Kpad - kc) : KC;
      __syncthreads();   // protect sW (and first pass: sA posenc/prev-layer writes)
      if (kcn == KC) {
        for (int idx = tid; idx < KC * 128; idx += THREADS) {
          int kk = idx & 31, c = idx >> 5, kg = kc + kk;
          sW[kk * WSTR + c] = (kg < Kin) ? Wg[c * Kin + kg] : 0.0f;
        }
      } else {  // kcn == 8 (layer 0 tail)
        for (int idx = tid; idx < 8 * 128; idx += THREADS) {
          int kk = idx & 7, c = idx >> 3, kg = kc + kk;
          sW[kk * WSTR + c] = (kg < Kin) ? Wg[c * Kin + kg] : 0.0f;
        }
      }
      __syncthreads();
      for (int kk = 0; kk < kcn; ++kk) {
        float a[8], w[8];
        *(float4*)&a[0] = *(const float4*)&sA[(kc + kk) * ROWS + 8*tr];
        *(float4*)&a[4] = *(const float4*)&sA[(kc + kk) * ROWS + 8*tr + 4];
        *(float4*)&w[0] = *(const float4*)&sW[kk * WSTR + 8*tc];
        *(float4*)&w[4] = *(const float4*)&sW[kk * WSTR + 8*tc + 4];
        #pragma unroll
        for (int i = 0; i < 8; ++i)
          #pragma unroll
          for (int j = 0; j < 8; ++j)
            acc[i][j] = fmaf(a[i], w[j], acc[i][j]);
      }
    }

    // activation: value rows get (leaky)relu; tangent rows get the mask
    #pragma unroll
    for (int h = 0; h < 2; ++h) {
      int iv = h * 4;
      #pragma unroll
      for (int j = 0; j < 8; ++j) {
        float hv = acc[iv][j];
        float m = (hv > 0.0f) ? 1.0f : slope;
        acc[iv][j]    = hv * m;
        acc[iv+1][j] *= m;
        acc[iv+2][j] *= m;
        acc[iv+3][j] *= m;
      }
    }

    __syncthreads();   // all reads of old sA done
    #pragma unroll
    for (int j = 0; j < 8; ++j) {   // transposed write: col becomes next layer's k
      float4 v0 = make_float4(acc[0][j], acc[1][j], acc[2][j], acc[3][j]);
      float4 v1 = make_float4(acc[4][j], acc[5][j], acc[6][j], acc[7][j]);
      *(float4*)&sA[(8*tc + j) * ROWS + 8*tr]     = v0;
      *(float4*)&sA[(8*tc + j) * ROWS + 8*tr + 4] = v1;
    }
  }
  __syncthreads();

  // ---- heads: 6 outputs (w0..2, v0..2) per row; bias only on value rows ----
  for (int idx = tid; idx < 6 * ROWS; idx += THREADS) {
    int r = idx & 63;
    int o = idx >> 6;
    const float* Wh = (o < 3) ? (Ww + o * 128) : (Wv + (o - 3) * 128);
    float s0 = 0.f, s1 = 0.f, s2 = 0.f, s3 = 0.f;
    for (int k = 0; k < 128; k += 4) {
      float4 wh = *(const float4*)&Wh[k];
      s0 = fmaf(sA[(k+0) * ROWS + r], wh.x, s0);
      s1 = fmaf(sA[(k+1) * ROWS + r], wh.y, s1);
      s2 = fmaf(sA[(k+2) * ROWS + r], wh.z, s2);
      s3 = fmaf(sA[(k+3) * ROWS + r], wh.w, s3);
    }
    float accd = (s0 + s1) + (s2 + s3);
    if ((r & 3) == 0) accd += (o < 3) ? bw[o] : bv[o - 3];
    sH[r * 8 + o] = accd;
  }
  __syncthreads();

  // ---- SE(3) epilogue + analytic forward-mode Jacobian, one thread per point ----
  if (tid < PPB) {
    const int p = tid;
    const int gp = p0 + p;
    float X[3] = { sX[p*3+0], sX[p*3+1], sX[p*3+2] };
    float w[3], v[3], dw[3][3], dv[3][3];
    const int rb = p * 4;
    #pragma unroll
    for (int i = 0; i < 3; ++i) {
      w[i] = sH[rb * 8 + i];
      v[i] = sH[rb * 8 + 3 + i];
      #pragma unroll
      for (int d = 0; d < 3; ++d) {
        dw[d][i] = sH[(rb + 1 + d) * 8 + i];
        dv[d][i] = sH[(rb + 1 + d) * 8 + 3 + i];
      }
    }
    float th  = sqrtf(w[0]*w[0] + w[1]*w[1] + w[2]*w[2]);
    float ith = 1.0f / th;
    float u[3]  = { w[0]*ith, w[1]*ith, w[2]*ith };
    float vh[3] = { v[0]*ith, v[1]*ith, v[2]*ith };
    float s = sinf(th), c = cosf(th);
    float C2 = 1.0f - c;
    float ths = th - s;
    // W u-hat identities: W a = u x a ; W^2 a = u (u.a) - a
    float uxx[3]; cross3(u, X, uxx);
    float udx = dot3(u, X);
    float uxv[3]; cross3(u, vh, uxv);
    float udv = dot3(u, vh);
    #pragma unroll
    for (int i = 0; i < 3; ++i) {
      float Rx = X[i] + s * uxx[i] + C2 * (u[i] * udx - X[i]);
      float tt = th * vh[i] + C2 * uxv[i] + ths * (u[i] * udv - vh[i]);
      out[gp*3 + i] = Rx + tt;
    }
    float* Jout = out + (size_t)NPTS * 3 + (size_t)gp * 9;
    #pragma unroll
    for (int d = 0; d < 3; ++d) {
      float dwv[3] = { dw[d][0], dw[d][1], dw[d][2] };
      float dvv[3] = { dv[d][0], dv[d][1], dv[d][2] };
      float dth = dot3(w, dwv) * ith;
      float du[3], dvhv[3];
      #pragma unroll
      for (int i = 0; i < 3; ++i) {
        du[i]   = (dwv[i] - u[i]  * dth) * ith;
        dvhv[i] = (dvv[i] - vh[i] * dth) * ith;
      }
      float ex[3] = { d == 0 ? 1.0f : 0.0f, d == 1 ? 1.0f : 0.0f, d == 2 ? 1.0f : 0.0f };
      float dsv  = c  * dth;
      float dC2  = s  * dth;
      float dths = C2 * dth;
      float duxx[3]; cross3(du, X, duxx);
      float uxe[3];  cross3(u, ex, uxe);
      float dudx = dot3(du, X) + u[d];                 // d(u.x), dx = e_d
      float duxv[3]; cross3(du, vh, duxv);
      float uxdv[3]; cross3(u, dvhv, uxdv);
      float dudv = dot3(du, vh) + dot3(u, dvhv);
      #pragma unroll
      for (int i = 0; i < 3; ++i) {
        float dRx = ex[i] + dsv * uxx[i] + s * (duxx[i] + uxe[i])
                  + dC2 * (u[i] * udx - X[i])
                  + C2 * (du[i] * udx + u[i] * dudx - ex[i]);
        float dt  = dth * vh[i] + th * dvhv[i] + dC2 * uxv[i]
                  + C2 * (duxv[i] + uxdv[i])
                  + dths * (u[i] * udv - vh[i])
                  + ths * (du[i] * udv + u[i] * dudv - dvhv[i]);
        Jout[i * 3 + d] = dRx + dt;   // J[n,i,d] = d warp_i / d x_d
      }
    }
  }
}

extern "C" void kernel_launch(void* const* d_in, const int* in_sizes, int n_in,
                              void* d_out, int out_size, void* d_ws, size_t ws_size,
                              hipStream_t stream) {
  const float* x    = (const float*)d_in[0];
  const float* W_in = (const float*)d_in[1];
  const float* b_in = (const float*)d_in[2];
  const float* Ws   = (const float*)d_in[3];
  const float* bs   = (const float*)d_in[4];
  const float* Ww   = (const float*)d_in[5];
  const float* bw   = (const float*)d_in[6];
  const float* Wv   = (const float*)d_in[7];
  const float* bv   = (const float*)d_in[8];
  const int*   itp  = (const int*)d_in[9];
  dim3 grid(NPTS / PPB);
  nerfies_fused<<<grid, THREADS, 0, stream>>>(x, W_in, b_in, Ws, bs, Ww, bw, Wv, bv, itp,
                                              (float*)d_out);
}

// Round 2
// 462.264 us; speedup vs baseline: 5.9239x; 5.9239x over previous
//
#include <hip/hip_runtime.h>
#include <math.h>

#define NPTS    131072
#define PPB     32           // points per block
#define ROWS    128          // 4 rows per point
#define THREADS 256          // 4 waves
#define NBLK    (NPTS / PPB) // 4096
#define SAS     136          // padded LDS row stride in bf16 elements (272 B)

typedef __attribute__((ext_vector_type(8))) short short8;
typedef __attribute__((ext_vector_type(4))) float f32x4;

__device__ __forceinline__ unsigned short f2bf(float f) {
  unsigned u = __float_as_uint(f);
  unsigned r = (u + 0x7fffu + ((u >> 16) & 1u)) >> 16;
  return (unsigned short)r;
}
__device__ __forceinline__ float bf2f(unsigned short b) {
  return __uint_as_float(((unsigned)b) << 16);
}
__device__ __forceinline__ void cross3(const float a[3], const float b[3], float o[3]) {
  o[0] = a[1]*b[2] - a[2]*b[1];
  o[1] = a[2]*b[0] - a[0]*b[2];
  o[2] = a[0]*b[1] - a[1]*b[0];
}
__device__ __forceinline__ float dot3(const float a[3], const float b[3]) {
  return a[0]*b[0] + a[1]*b[1] + a[2]*b[2];
}

// ---- pre-convert all MLP weights to bf16 in workspace: 7 x [128][128] ----
// layer 0: k<39 from W_in[c][k], else 0.  layers 1..6: Ws.
__global__ void convert_weights(const float* __restrict__ W_in,
                                const float* __restrict__ Ws,
                                unsigned short* __restrict__ wsW) {
  int idx = blockIdx.x * 256 + threadIdx.x;          // 0 .. 7*16384-1
  if (idx >= 7 * 16384) return;
  int l = idx >> 14;
  int r = idx & 16383;
  int c = r >> 7;
  int k = r & 127;
  float v;
  if (l == 0) v = (k < 39) ? W_in[c * 39 + k] : 0.0f;
  else        v = Ws[(l - 1) * 16384 + c * 128 + k];
  wsW[idx] = f2bf(v);
}

__global__ __launch_bounds__(THREADS, 2)
void nerfies_mfma(const float* __restrict__ x,
                  const float* __restrict__ b_in,
                  const float* __restrict__ bs,
                  const float* __restrict__ Ww,
                  const float* __restrict__ bw,
                  const float* __restrict__ Wv,
                  const float* __restrict__ bv,
                  const unsigned short* __restrict__ wsW,  // 7*[128][128] bf16
                  const int* __restrict__ iterp,
                  float* __restrict__ out)
{
  __shared__ __align__(16) unsigned short sA[ROWS * SAS];  // activations [row][k]
  __shared__ __align__(16) unsigned short sW[128 * SAS];   // weights    [col][k]
  __shared__ __align__(16) float sH[ROWS * 8];             // head outs  [row][o]
  __shared__ __align__(16) float sX[PPB * 3];

  const int tid  = threadIdx.x;
  const int lane = tid & 63;
  const int wv   = tid >> 6;        // wave 0..3
  const int n16  = lane & 15;       // tile col / A-row-in-tile
  const int quad = lane >> 4;       // 0..3
  const int p0   = blockIdx.x * PPB;

  // ---- prologue: issue W0 loads, zero sA, load sX ----
  int4 wpre[8];
  #pragma unroll
  for (int i = 0; i < 8; ++i) {
    int g = i * 256 + tid;          // chunk id 0..2047
    int c = g >> 4, kc = g & 15;
    wpre[i] = *(const int4*)(wsW + c * 128 + kc * 8);
  }
  for (int i = tid; i < ROWS * SAS / 8; i += THREADS)
    *(int4*)&sA[i * 8] = make_int4(0, 0, 0, 0);
  if (tid < PPB * 3) sX[tid] = x[p0 * 3 + tid];
  // write W0 into sW (waits on wpre internally)
  #pragma unroll
  for (int i = 0; i < 8; ++i) {
    int g = i * 256 + tid;
    int c = g >> 4, kc = g & 15;
    *(int4*)&sW[c * SAS + kc * 8] = wpre[i];
  }
  // prefetch W1
  #pragma unroll
  for (int i = 0; i < 8; ++i) {
    int g = i * 256 + tid;
    int c = g >> 4, kc = g & 15;
    wpre[i] = *(const int4*)(wsW + 16384 + c * 128 + kc * 8);
  }

  // iter decode (robust: int32 or float32 payload)
  int iraw = iterp[0];
  float it = (iraw > 0 && iraw < 100000000) ? (float)iraw : ((const float*)iterp)[0];
  const float aM = 6.0f * it / 3000.0f;
  float wa[6], mulf[6];
  #pragma unroll
  for (int j = 0; j < 6; ++j) {
    float t = fminf(fmaxf(aM - (float)j, 0.0f), 1.0f);
    wa[j]   = (1.0f - cosf(t * 3.14f)) * 0.5f;
    mulf[j] = exp2f((float)(j - 3)) * 3.14f;
  }
  __syncthreads();   // sX + sA zeros visible

  // ---- posenc into sA[row][k], k<40 (rest stays 0) ----
  for (int idx = tid; idx < ROWS * 40; idx += THREADS) {
    int row = idx / 40;
    int k   = idx - row * 40;
    int p = row >> 2, d = row & 3;
    float val = 0.0f;
    if (k < 3) {
      val = (d == 0) ? sX[p * 3 + k] : ((k == d - 1) ? 1.0f : 0.0f);
    } else if (k < 39) {
      int kk = k - 3;
      int i  = kk / 12;
      int rm = kk - i * 12;
      int t  = rm / 6;
      int j  = rm - t * 6;
      float ang = sX[p * 3 + i] * mulf[j];
      float sv = sinf(ang), cv = cosf(ang);
      if (d == 0)          val = (t == 0 ? sv : cv) * wa[j];
      else if (i == d - 1) val = (t == 0 ? cv : -sv) * (mulf[j] * wa[j]);
    }
    sA[row * SAS + k] = f2bf(val);
  }

  // ---- 7 MFMA layers ----
  const unsigned short* pA0 = &sA[(wv * 32 + n16) * SAS];
  const unsigned short* pA1 = pA0 + 16 * SAS;
  const int koffq = quad * 8;

  for (int l = 0; l < 7; ++l) {
    __syncthreads();   // barrier #1: sA inputs + sW weights ready

    // issue prefetch of W_{l+2}? no: wpre holds W_{l+1}; nothing to issue here yet.
    const float* bg = (l == 0) ? b_in : (bs + (l - 1) * 128);
    const float slope = (l == 0) ? 0.01f : 0.0f;

    f32x4 acc[2][8];
    #pragma unroll
    for (int ct = 0; ct < 8; ++ct) {
      float b = bg[ct * 16 + n16];
      acc[0][ct] = (f32x4){b, 0.f, 0.f, 0.f};
      acc[1][ct] = (f32x4){b, 0.f, 0.f, 0.f};
    }

    #pragma unroll 1
    for (int ks = 0; ks < 4; ++ks) {
      const int ko = koffq + ks * 32;
      short8 a0 = *(const short8*)(pA0 + ko);
      short8 a1 = *(const short8*)(pA1 + ko);
      #pragma unroll
      for (int ct = 0; ct < 8; ++ct) {
        short8 b = *(const short8*)(&sW[(ct * 16 + n16) * SAS] + ko);
        acc[0][ct] = __builtin_amdgcn_mfma_f32_16x16x32_bf16(a0, b, acc[0][ct], 0, 0, 0);
        acc[1][ct] = __builtin_amdgcn_mfma_f32_16x16x32_bf16(a1, b, acc[1][ct], 0, 0, 0);
      }
    }

    // activation in-register: reg0 = value row, regs 1..3 = tangents
    #pragma unroll
    for (int rt = 0; rt < 2; ++rt)
      #pragma unroll
      for (int ct = 0; ct < 8; ++ct) {
        float hv = acc[rt][ct][0];
        float m = (hv > 0.0f) ? 1.0f : slope;
        acc[rt][ct][0] = hv * m;
        acc[rt][ct][1] *= m;
        acc[rt][ct][2] *= m;
        acc[rt][ct][3] *= m;
      }

    __syncthreads();   // barrier #2: all reads of sA/sW done

    // write C -> sA (next layer's input), cols become k
    #pragma unroll
    for (int rt = 0; rt < 2; ++rt) {
      int rowb = wv * 32 + rt * 16 + quad * 4;
      #pragma unroll
      for (int ct = 0; ct < 8; ++ct) {
        unsigned short* dst = &sA[rowb * SAS + ct * 16 + n16];
        dst[0]       = f2bf(acc[rt][ct][0]);
        dst[SAS]     = f2bf(acc[rt][ct][1]);
        dst[2 * SAS] = f2bf(acc[rt][ct][2]);
        dst[3 * SAS] = f2bf(acc[rt][ct][3]);
      }
    }

    if (l < 6) {
      // write W_{l+1} into sW, then prefetch W_{l+2}
      #pragma unroll
      for (int i = 0; i < 8; ++i) {
        int g = i * 256 + tid;
        int c = g >> 4, kc = g & 15;
        *(int4*)&sW[c * SAS + kc * 8] = wpre[i];
      }
      if (l < 5) {
        #pragma unroll
        for (int i = 0; i < 8; ++i) {
          int g = i * 256 + tid;
          int c = g >> 4, kc = g & 15;
          wpre[i] = *(const int4*)(wsW + (l + 2) * 16384 + c * 128 + kc * 8);
        }
      }
    }
  }
  __syncthreads();   // final activations visible

  // ---- heads: 6 outs x 128 rows ----
  for (int idx = tid; idx < 6 * ROWS; idx += THREADS) {
    int o = idx >> 7;
    int r = idx & 127;
    const float* Wh = (o < 3) ? (Ww + o * 128) : (Wv + (o - 3) * 128);
    const unsigned short* ar = &sA[r * SAS];
    float s = 0.0f;
    #pragma unroll 4
    for (int c = 0; c < 16; ++c) {
      short8 av = *(const short8*)(ar + c * 8);
      float4 w1 = *(const float4*)(Wh + c * 8);
      float4 w2 = *(const float4*)(Wh + c * 8 + 4);
      s = fmaf(bf2f((unsigned short)av[0]), w1.x, s);
      s = fmaf(bf2f((unsigned short)av[1]), w1.y, s);
      s = fmaf(bf2f((unsigned short)av[2]), w1.z, s);
      s = fmaf(bf2f((unsigned short)av[3]), w1.w, s);
      s = fmaf(bf2f((unsigned short)av[4]), w2.x, s);
      s = fmaf(bf2f((unsigned short)av[5]), w2.y, s);
      s = fmaf(bf2f((unsigned short)av[6]), w2.z, s);
      s = fmaf(bf2f((unsigned short)av[7]), w2.w, s);
    }
    if ((r & 3) == 0) s += (o < 3) ? bw[o] : bv[o - 3];
    sH[r * 8 + o] = s;
  }
  __syncthreads();

  // ---- SE(3) epilogue + forward-mode Jacobian, one thread per point ----
  if (tid < PPB) {
    const int p = tid;
    const int gp = p0 + p;
    float X[3] = { sX[p*3+0], sX[p*3+1], sX[p*3+2] };
    float w[3], v[3], dw[3][3], dv[3][3];
    const int rb = p * 4;
    #pragma unroll
    for (int i = 0; i < 3; ++i) {
      w[i] = sH[rb * 8 + i];
      v[i] = sH[rb * 8 + 3 + i];
      #pragma unroll
      for (int d = 0; d < 3; ++d) {
        dw[d][i] = sH[(rb + 1 + d) * 8 + i];
        dv[d][i] = sH[(rb + 1 + d) * 8 + 3 + i];
      }
    }
    float th  = sqrtf(w[0]*w[0] + w[1]*w[1] + w[2]*w[2]);
    float ith = 1.0f / th;
    float u[3]  = { w[0]*ith, w[1]*ith, w[2]*ith };
    float vh[3] = { v[0]*ith, v[1]*ith, v[2]*ith };
    float s = sinf(th), c = cosf(th);
    float C2 = 1.0f - c;
    float ths = th - s;
    float uxx[3]; cross3(u, X, uxx);
    float udx = dot3(u, X);
    float uxv[3]; cross3(u, vh, uxv);
    float udv = dot3(u, vh);
    #pragma unroll
    for (int i = 0; i < 3; ++i) {
      float Rx = X[i] + s * uxx[i] + C2 * (u[i] * udx - X[i]);
      float tt = th * vh[i] + C2 * uxv[i] + ths * (u[i] * udv - vh[i]);
      out[gp*3 + i] = Rx + tt;
    }
    float* Jout = out + (size_t)NPTS * 3 + (size_t)gp * 9;
    #pragma unroll
    for (int d = 0; d < 3; ++d) {
      float dwv[3] = { dw[d][0], dw[d][1], dw[d][2] };
      float dvv[3] = { dv[d][0], dv[d][1], dv[d][2] };
      float dth = dot3(w, dwv) * ith;
      float du[3], dvhv[3];
      #pragma unroll
      for (int i = 0; i < 3; ++i) {
        du[i]   = (dwv[i] - u[i]  * dth) * ith;
        dvhv[i] = (dvv[i] - vh[i] * dth) * ith;
      }
      float ex[3] = { d == 0 ? 1.0f : 0.0f, d == 1 ? 1.0f : 0.0f, d == 2 ? 1.0f : 0.0f };
      float dsv  = c  * dth;
      float dC2  = s  * dth;
      float dths = C2 * dth;
      float duxx[3]; cross3(du, X, duxx);
      float uxe[3];  cross3(u, ex, uxe);
      float dudx = dot3(du, X) + u[d];
      float duxv[3]; cross3(du, vh, duxv);
      float uxdv[3]; cross3(u, dvhv, uxdv);
      float dudv = dot3(du, vh) + dot3(u, dvhv);
      #pragma unroll
      for (int i = 0; i < 3; ++i) {
        float dRx = ex[i] + dsv * uxx[i] + s * (duxx[i] + uxe[i])
                  + dC2 * (u[i] * udx - X[i])
                  + C2 * (du[i] * udx + u[i] * dudx - ex[i]);
        float dt  = dth * vh[i] + th * dvhv[i] + dC2 * uxv[i]
                  + C2 * (duxv[i] + uxdv[i])
                  + dths * (u[i] * udv - vh[i])
                  + ths * (du[i] * udv + u[i] * dudv - dvhv[i]);
        Jout[i * 3 + d] = dRx + dt;
      }
    }
  }
}

extern "C" void kernel_launch(void* const* d_in, const int* in_sizes, int n_in,
                              void* d_out, int out_size, void* d_ws, size_t ws_size,
                              hipStream_t stream) {
  const float* x    = (const float*)d_in[0];
  const float* W_in = (const float*)d_in[1];
  const float* b_in = (const float*)d_in[2];
  const float* Ws   = (const float*)d_in[3];
  const float* bs   = (const float*)d_in[4];
  const float* Ww   = (const float*)d_in[5];
  const float* bw   = (const float*)d_in[6];
  const float* Wv   = (const float*)d_in[7];
  const float* bv   = (const float*)d_in[8];
  const int*   itp  = (const int*)d_in[9];
  unsigned short* wsW = (unsigned short*)d_ws;   // 7*16384 bf16 = 224 KB

  convert_weights<<<dim3((7 * 16384 + 255) / 256), dim3(256), 0, stream>>>(W_in, Ws, wsW);
  nerfies_mfma<<<dim3(NBLK), dim3(THREADS), 0, stream>>>(
      x, b_in, bs, Ww, bw, Wv, bv, wsW, itp, (float*)d_out);
}

// Round 3
// 301.300 us; speedup vs baseline: 9.0887x; 1.5342x over previous
//
#include <hip/hip_runtime.h>
#include <math.h>

#define NPTS    131072
#define PPB     32            // points per block
#define ROWS    128           // 4 rows per point
#define THREADS 256           // 4 waves (2x2 wave grid)
#define NBLK    (NPTS / PPB)  // 4096
#define HOFF    (7 * 16384)   // head-weight offset in wsW (bf16 elems)

typedef __attribute__((ext_vector_type(8))) short short8;
typedef __attribute__((ext_vector_type(4))) float f32x4;

__device__ __forceinline__ unsigned short f2bf(float f) {
  unsigned u = __float_as_uint(f);
  unsigned r = (u + 0x7fffu + ((u >> 16) & 1u)) >> 16;
  return (unsigned short)r;
}
#if defined(__has_builtin)
#if __has_builtin(__builtin_amdgcn_cvt_pk_bf16_f32)
#define HAVE_PK_BF16 1
#endif
#endif
__device__ __forceinline__ unsigned pk2(float lo, float hi) {
#ifdef HAVE_PK_BF16
  auto v = __builtin_amdgcn_cvt_pk_bf16_f32(lo, hi);
  unsigned u; __builtin_memcpy(&u, &v, 4); return u;
#else
  return (unsigned)f2bf(lo) | ((unsigned)f2bf(hi) << 16);
#endif
}
__device__ __forceinline__ void gld16(const unsigned short* g, unsigned short* l) {
  __builtin_amdgcn_global_load_lds(
      (const __attribute__((address_space(1))) unsigned int*)(g),
      (__attribute__((address_space(3))) unsigned int*)(l), 16, 0, 0);
}
__device__ __forceinline__ void cross3(const float a[3], const float b[3], float o[3]) {
  o[0] = a[1]*b[2] - a[2]*b[1];
  o[1] = a[2]*b[0] - a[0]*b[2];
  o[2] = a[0]*b[1] - a[1]*b[0];
}
__device__ __forceinline__ float dot3(const float a[3], const float b[3]) {
  return a[0]*b[0] + a[1]*b[1] + a[2]*b[2];
}

// sA element (r,k) lives at r*128 + ((k>>3)^(r&15))*8 + (k&7)   (XOR chunk swizzle)
__device__ __forceinline__ void swrite(unsigned short* sA, int r, int k, float v) {
  int off = r * 128 + ((((k >> 3) ^ (r & 15))) << 3) + (k & 7);
  sA[off] = f2bf(v);
}

// ---- weights -> bf16 workspace: 7x[128cols][128k] MLP + 16x128 heads ----
__global__ void convert_weights(const float* __restrict__ W_in,
                                const float* __restrict__ Ws,
                                const float* __restrict__ Ww,
                                const float* __restrict__ Wv,
                                unsigned short* __restrict__ wsW) {
  int idx = blockIdx.x * 256 + threadIdx.x;
  if (idx >= HOFF + 2048) return;
  float v;
  if (idx < HOFF) {
    int l = idx >> 14, r = idx & 16383, c = r >> 7, k = r & 127;
    if (l == 0) v = (k < 39) ? W_in[c * 39 + k] : 0.0f;
    else        v = Ws[(l - 1) * 16384 + c * 128 + k];
  } else {
    int r = idx - HOFF, o = r >> 7, k = r & 127;
    v = (o < 3) ? Ww[o * 128 + k] : (o < 6) ? Wv[(o - 3) * 128 + k] : 0.0f;
  }
  wsW[idx] = f2bf(v);
}

// One MLP layer: sA (acts, swizzled) x sW (weights, swizzled) -> sA.
// Operand swap: A-operand = weights (m=c), B-operand = acts (n=r).
template <int KMAX, bool LEAKY>
__device__ __forceinline__ void layer_pass(unsigned short* sA, unsigned short* sW,
                                           const float* __restrict__ bg,
                                           const unsigned short* __restrict__ nextW,
                                           int n16, int quad, int wr, int wc,
                                           int lane, int wv) {
  const bool isv = (n16 & 3) == 0;      // this lane's rows are value rows
  f32x4 acc[4][4];
  #pragma unroll
  for (int ct = 0; ct < 4; ++ct) {
    float4 b = *(const float4*)(bg + wc * 64 + ct * 16 + quad * 4);
    f32x4 ib;
    ib[0] = isv ? b.x : 0.0f; ib[1] = isv ? b.y : 0.0f;
    ib[2] = isv ? b.z : 0.0f; ib[3] = isv ? b.w : 0.0f;
    acc[0][ct] = ib; acc[1][ct] = ib; acc[2][ct] = ib; acc[3][ct] = ib;
  }

  #pragma unroll
  for (int ks = 0; ks < KMAX; ++ks) {
    const int ch = (((quad + 4 * ks) ^ n16)) << 3;   // swizzled chunk offset (u16)
    short8 aw[4], bx[4];
    #pragma unroll
    for (int ct = 0; ct < 4; ++ct)
      aw[ct] = *(const short8*)(sW + (wc * 64 + ct * 16 + n16) * 128 + ch);
    #pragma unroll
    for (int rt = 0; rt < 4; ++rt)
      bx[rt] = *(const short8*)(sA + (wr * 64 + rt * 16 + n16) * 128 + ch);
    #pragma unroll
    for (int rt = 0; rt < 4; ++rt)
      #pragma unroll
      for (int ct = 0; ct < 4; ++ct)
        acc[rt][ct] = __builtin_amdgcn_mfma_f32_16x16x32_bf16(aw[ct], bx[rt], acc[rt][ct], 0, 0, 0);
  }

  // activation: mask comes from the point's value row = lane (lane & ~3)
  #pragma unroll
  for (int rt = 0; rt < 4; ++rt)
    #pragma unroll
    for (int ct = 0; ct < 4; ++ct)
      #pragma unroll
      for (int e = 0; e < 4; ++e) {
        float a = acc[rt][ct][e];
        float lv = LEAKY ? (a > 0.0f ? a : a * 0.01f) : fmaxf(a, 0.0f);
        float sv = __shfl(lv, lane & ~3);
        acc[rt][ct][e] = LEAKY ? (sv > 0.0f ? a : a * 0.01f)
                               : (sv > 0.0f ? a : 0.0f);
      }

  __syncthreads();   // everyone done reading sA/sW

  if (nextW) {       // async-DMA next layer's weights into sW (swizzled)
    #pragma unroll
    for (int i = 0; i < 8; ++i) {
      int o = (wv * 8 + i) * 64 + lane;
      int c = o >> 4, kcs = o & 15, kc = kcs ^ (c & 15);
      gld16(nextW + c * 128 + kc * 8, sW + (wv * 8 + i) * 512);
    }
  }

  // packed C-writeback: 4 consecutive cols per lane -> one ds_write_b64
  #pragma unroll
  for (int rt = 0; rt < 4; ++rt) {
    int r = wr * 64 + rt * 16 + n16;
    #pragma unroll
    for (int ct = 0; ct < 4; ++ct) {
      int kc = wc * 8 + ct * 2 + (quad >> 1);
      int off = r * 128 + ((kc ^ n16) << 3) + (quad & 1) * 4;
      unsigned lo = pk2(acc[rt][ct][0], acc[rt][ct][1]);
      unsigned hi = pk2(acc[rt][ct][2], acc[rt][ct][3]);
      *(uint2*)(sA + off) = make_uint2(lo, hi);
    }
  }
  __syncthreads();   // sA(l+1) + sW(l+1) ready
}

__global__ __launch_bounds__(THREADS, 2)
void nerfies_mfma(const float* __restrict__ x,
                  const float* __restrict__ b_in,
                  const float* __restrict__ bs,
                  const float* __restrict__ bw,
                  const float* __restrict__ bv,
                  const unsigned short* __restrict__ wsW,
                  const int* __restrict__ iterp,
                  float* __restrict__ out)
{
  __shared__ __align__(16) unsigned short sA[128 * 128];  // 32 KB acts (swizzled)
  __shared__ __align__(16) unsigned short sW[128 * 128];  // 32 KB weights (swizzled)
  __shared__ __align__(16) float sX[PPB * 3];
  float* sH = (float*)sW;                                 // heads alias sW (after last use)

  const int tid  = threadIdx.x;
  const int lane = tid & 63;
  const int wv   = tid >> 6;
  const int n16  = lane & 15;
  const int quad = lane >> 4;
  const int wr   = wv >> 1;   // row half
  const int wc   = wv & 1;    // col half
  const int p0   = blockIdx.x * PPB;

  // prologue: DMA layer-0 weights, zero sA, load coords
  #pragma unroll
  for (int i = 0; i < 8; ++i) {
    int o = (wv * 8 + i) * 64 + lane;
    int c = o >> 4, kcs = o & 15, kc = kcs ^ (c & 15);
    gld16(wsW + c * 128 + kc * 8, sW + (wv * 8 + i) * 512);
  }
  for (int i = tid; i < 128 * 128 / 8; i += THREADS)
    *(int4*)(sA + i * 8) = make_int4(0, 0, 0, 0);
  if (tid < PPB * 3) sX[tid] = x[p0 * 3 + tid];

  int iraw = iterp[0];
  float it = (iraw > 0 && iraw < 100000000) ? (float)iraw : ((const float*)iterp)[0];
  const float aM = 6.0f * it / 3000.0f;
  __syncthreads();   // zeros + sX visible; sW0 DMA drained

  // posenc: value rows + matching tangent entries only (rest stays 0)
  if (tid < PPB * 3) {
    int p = tid / 3, a = tid - p * 3;
    swrite(sA, 4 * p, a, sX[p * 3 + a]);
    swrite(sA, 4 * p + 1 + a, a, 1.0f);
  }
  for (int itx = tid; itx < PPB * 18; itx += THREADS) {
    int p = itx / 18, rem = itx - p * 18;
    int a = rem / 6, j = rem - a * 6;
    float mj = exp2f((float)(j - 3)) * 3.14f;
    float t  = fminf(fmaxf(aM - (float)j, 0.0f), 1.0f);
    float wj = (1.0f - cosf(t * 3.14f)) * 0.5f;
    float ang = sX[p * 3 + a] * mj;
    float sv = sinf(ang), cv = cosf(ang);
    int r0 = 4 * p, ksin = 3 + a * 12 + j, kcos = ksin + 6;
    swrite(sA, r0, ksin, sv * wj);
    swrite(sA, r0, kcos, cv * wj);
    swrite(sA, r0 + 1 + a, ksin, cv * mj * wj);
    swrite(sA, r0 + 1 + a, kcos, -sv * mj * wj);
  }
  __syncthreads();   // sA(input) ready

  // 7 layers: layer0 leaky(K=64 covers the 40 used), then 6 relu layers
  layer_pass<2, true >(sA, sW, b_in, wsW + 16384, n16, quad, wr, wc, lane, wv);
  layer_pass<4, false>(sA, sW, bs + 0 * 128, wsW + 2 * 16384, n16, quad, wr, wc, lane, wv);
  layer_pass<4, false>(sA, sW, bs + 1 * 128, wsW + 3 * 16384, n16, quad, wr, wc, lane, wv);
  layer_pass<4, false>(sA, sW, bs + 2 * 128, wsW + 4 * 16384, n16, quad, wr, wc, lane, wv);
  layer_pass<4, false>(sA, sW, bs + 3 * 128, wsW + 5 * 16384, n16, quad, wr, wc, lane, wv);
  layer_pass<4, false>(sA, sW, bs + 4 * 128, wsW + 6 * 16384, n16, quad, wr, wc, lane, wv);
  layer_pass<4, false>(sA, sW, bs + 5 * 128, nullptr,         n16, quad, wr, wc, lane, wv);

  // heads via MFMA: A = head weights (16 rows, 6 used) from global, B = acts
  {
    f32x4 hacc[2];
    hacc[0] = (f32x4){0.f, 0.f, 0.f, 0.f};
    hacc[1] = (f32x4){0.f, 0.f, 0.f, 0.f};
    const unsigned short* hw = wsW + HOFF;
    #pragma unroll
    for (int ks = 0; ks < 4; ++ks) {
      const int ch = (((quad + 4 * ks) ^ n16)) << 3;
      short8 aw = *(const short8*)(hw + n16 * 128 + quad * 8 + ks * 32);
      #pragma unroll
      for (int rt = 0; rt < 2; ++rt) {
        short8 bx = *(const short8*)(sA + (wv * 32 + rt * 16 + n16) * 128 + ch);
        hacc[rt] = __builtin_amdgcn_mfma_f32_16x16x32_bf16(aw, bx, hacc[rt], 0, 0, 0);
      }
    }
    #pragma unroll
    for (int rt = 0; rt < 2; ++rt) {
      int r = wv * 32 + rt * 16 + n16;          // D: col=lane&15 -> row r; rows=o
      *(float4*)(sH + r * 16 + quad * 4) =
          make_float4(hacc[rt][0], hacc[rt][1], hacc[rt][2], hacc[rt][3]);
    }
  }
  __syncthreads();   // sH ready

  // SE(3) epilogue + forward-mode Jacobian, one thread per point
  if (tid < PPB) {
    const int p = tid;
    const int gp = p0 + p;
    float X[3] = { sX[p*3+0], sX[p*3+1], sX[p*3+2] };
    float w[3], v[3], dw[3][3], dv[3][3];
    const int rb = p * 4;
    #pragma unroll
    for (int i = 0; i < 3; ++i) {
      w[i] = sH[rb * 16 + i]       + bw[i];
      v[i] = sH[rb * 16 + 3 + i]   + bv[i];
      #pragma unroll
      for (int d = 0; d < 3; ++d) {
        dw[d][i] = sH[(rb + 1 + d) * 16 + i];
        dv[d][i] = sH[(rb + 1 + d) * 16 + 3 + i];
      }
    }
    float th  = sqrtf(w[0]*w[0] + w[1]*w[1] + w[2]*w[2]);
    float ith = 1.0f / th;
    float u[3]  = { w[0]*ith, w[1]*ith, w[2]*ith };
    float vh[3] = { v[0]*ith, v[1]*ith, v[2]*ith };
    float s = sinf(th), c = cosf(th);
    float C2 = 1.0f - c;
    float ths = th - s;
    float uxx[3]; cross3(u, X, uxx);
    float udx = dot3(u, X);
    float uxv[3]; cross3(u, vh, uxv);
    float udv = dot3(u, vh);
    #pragma unroll
    for (int i = 0; i < 3; ++i) {
      float Rx = X[i] + s * uxx[i] + C2 * (u[i] * udx - X[i]);
      float tt = th * vh[i] + C2 * uxv[i] + ths * (u[i] * udv - vh[i]);
      out[gp*3 + i] = Rx + tt;
    }
    float* Jout = out + (size_t)NPTS * 3 + (size_t)gp * 9;
    #pragma unroll
    for (int d = 0; d < 3; ++d) {
      float dwv[3] = { dw[d][0], dw[d][1], dw[d][2] };
      float dvv[3] = { dv[d][0], dv[d][1], dv[d][2] };
      float dth = dot3(w, dwv) * ith;
      float du[3], dvhv[3];
      #pragma unroll
      for (int i = 0; i < 3; ++i) {
        du[i]   = (dwv[i] - u[i]  * dth) * ith;
        dvhv[i] = (dvv[i] - vh[i] * dth) * ith;
      }
      float ex[3] = { d == 0 ? 1.0f : 0.0f, d == 1 ? 1.0f : 0.0f, d == 2 ? 1.0f : 0.0f };
      float dsv  = c  * dth;
      float dC2  = s  * dth;
      float dths = C2 * dth;
      float duxx[3]; cross3(du, X, duxx);
      float uxe[3];  cross3(u, ex, uxe);
      float dudx = dot3(du, X) + u[d];
      float duxv[3]; cross3(du, vh, duxv);
      float uxdv[3]; cross3(u, dvhv, uxdv);
      float dudv = dot3(du, vh) + dot3(u, dvhv);
      #pragma unroll
      for (int i = 0; i < 3; ++i) {
        float dRx = ex[i] + dsv * uxx[i] + s * (duxx[i] + uxe[i])
                  + dC2 * (u[i] * udx - X[i])
                  + C2 * (du[i] * udx + u[i] * dudx - ex[i]);
        float dt  = dth * vh[i] + th * dvhv[i] + dC2 * uxv[i]
                  + C2 * (duxv[i] + uxdv[i])
                  + dths * (u[i] * udv - vh[i])
                  + ths * (du[i] * udv + u[i] * dudv - dvhv[i]);
        Jout[i * 3 + d] = dRx + dt;
      }
    }
  }
}

extern "C" void kernel_launch(void* const* d_in, const int* in_sizes, int n_in,
                              void* d_out, int out_size, void* d_ws, size_t ws_size,
                              hipStream_t stream) {
  const float* x    = (const float*)d_in[0];
  const float* W_in = (const float*)d_in[1];
  const float* b_in = (const float*)d_in[2];
  const float* Ws   = (const float*)d_in[3];
  const float* bs   = (const float*)d_in[4];
  const float* Ww   = (const float*)d_in[5];
  const float* bw   = (const float*)d_in[6];
  const float* Wv   = (const float*)d_in[7];
  const float* bv   = (const float*)d_in[8];
  const int*   itp  = (const int*)d_in[9];
  unsigned short* wsW = (unsigned short*)d_ws;   // (7*16384 + 2048) bf16

  convert_weights<<<dim3((HOFF + 2048 + 255) / 256), dim3(256), 0, stream>>>(
      W_in, Ws, Ww, Wv, wsW);
  nerfies_mfma<<<dim3(NBLK), dim3(THREADS), 0, stream>>>(
      x, b_in, bs, bw, bv, wsW, itp, (float*)d_out);
}